// Round 9
// baseline (552.715 us; speedup 1.0000x reference)
//
#include <hip/hip_runtime.h>
#include <cstdint>

#pragma clang fp contract(off)

// ---------------------------------------------------------------------------
// threefry2x32 with key (0, 42)  [= jax.random.key(42)]
// Partitionable path (JAX >= 0.4.30 default): per element i, counter is the
// 64-bit flat index split as (hi, lo) = (0, i); output bits = x0 ^ x1.
// ---------------------------------------------------------------------------
__device__ __forceinline__ uint32_t rotl32(uint32_t x, uint32_t r) {
  return (x << r) | (x >> (32u - r));
}

__device__ __forceinline__ uint32_t threefry_bits(uint32_t idx) {
  const uint32_t ks0 = 0u;
  const uint32_t ks1 = 42u;
  const uint32_t ks2 = 0x1BD11BDAu ^ 0u ^ 42u;  // parity constant ^ k1 ^ k2
  uint32_t x0 = 0u + ks0;    // counter hi word
  uint32_t x1 = idx + ks1;   // counter lo word
#define TF_R(r) { x0 += x1; x1 = rotl32(x1, r); x1 ^= x0; }
  // round group 0: rotations {13,15,26,6}
  TF_R(13u) TF_R(15u) TF_R(26u) TF_R(6u)
  x0 += ks1; x1 += ks2 + 1u;
  // group 1: {17,29,16,24}
  TF_R(17u) TF_R(29u) TF_R(16u) TF_R(24u)
  x0 += ks2; x1 += ks0 + 2u;
  // group 2
  TF_R(13u) TF_R(15u) TF_R(26u) TF_R(6u)
  x0 += ks0; x1 += ks1 + 3u;
  // group 3
  TF_R(17u) TF_R(29u) TF_R(16u) TF_R(24u)
  x0 += ks1; x1 += ks2 + 4u;
  // group 4
  TF_R(13u) TF_R(15u) TF_R(26u) TF_R(6u)
  x0 += ks2; x1 += ks0 + 5u;
#undef TF_R
  return x0 ^ x1;  // 32-bit partitionable random bits
}

// ---------------------------------------------------------------------------
// XLA GPU tanh f32: llvm_ir::EmitFastTanh (Eigen rational approximation),
// with_fma=false variant: clamp +-7.90531110763549805, |x|<0.0004 -> x.
// All mul/add individually rounded (contract off).
// ---------------------------------------------------------------------------
__device__ __forceinline__ float xla_fast_tanh(float x) {
  const float kClamp = 7.90531110763549805f;
  float abs_x = fabsf(x);
  float xc = fminf(fmaxf(x, -kClamp), kClamp);
  float x2 = xc * xc;
  float num = -2.76076847742355e-16f;
  num = num * x2; num = num + 2.00018790482477e-13f;
  num = num * x2; num = num + -8.60467152213735e-11f;
  num = num * x2; num = num + 5.12229709037114e-08f;
  num = num * x2; num = num + 1.48572235717979e-05f;
  num = num * x2; num = num + 6.37261928875436e-04f;
  num = num * x2; num = num + 4.89352455891786e-03f;
  num = xc * num;
  float den = 1.19825839466702e-06f;
  den = den * x2; den = den + 1.18534705686654e-04f;
  den = den * x2; den = den + 2.26843463243900e-03f;
  den = den * x2; den = den + 4.89352518554385e-03f;
  float r = num / den;
  return (abs_x < 0.0004f) ? x : r;
}

// ---------------------------------------------------------------------------
// One element of the reference, fp32 op-for-op as XLA emits it.
// ---------------------------------------------------------------------------
__device__ __forceinline__ void compute_one(float in_v, float ang_v, float lr_v,
                                            uint32_t idx, float& meas,
                                            float& nang) {
  const float kHalfPi = 1.5707963267948966f;   // rounds to 0x3FC90FDB
  const float kSinG   = 0.7071067811865476f;   // sin(pi/4), rounds to 0x3F3504F3

  // thetas = (pi/2) * (last_res - tanh(input / 0.5));  /0.5 simplified to *2
  float t = xla_fast_tanh(in_v * 2.0f);
  float theta = kHalfPi * (lr_v - t);
  float temp = ang_v + theta;
  float h = temp * 0.5f;                        // temp_angles / 2
  float be = sinf(h);                           // __ocml_sin_f32 (matches XLA)
  float co = cosf(h);                           // __ocml_cos_f32
  float exp_z = (co * co) - (be * be);          // cos^2 - sin^2, no FMA
  float e = exp_z * kSinG;                      // exp_z_anc
  float p0 = fmaxf((1.0f + e) * 0.5f, 0.0f);
  float p1 = fmaxf((1.0f - e) * 0.5f, 0.0f);
  float ratio = p0 / (p0 + p1);

  // u = jax.random.uniform(key(42)):  bitcast((bits>>9)|0x3f800000) - 1
  uint32_t bits = threefry_bits(idx);
  float u = __uint_as_float((bits >> 9) | 0x3f800000u) - 1.0f;
  float m = (u < ratio) ? 1.0f : -1.0f;

  // side = betas * sqrt((1 - m*sinG) / (1 + m*exp_z_anc)), clipped to [-1,1]
  float numr = 1.0f - m * kSinG;
  float denr = 1.0f + m * e;
  float side = be * sqrtf(numr / denr);
  side = fminf(fmaxf(side, -1.0f), 1.0f);

  // new_angles = 2 * arcsin(side); JAX lowers asin(x)=2*atan2(x,1+sqrt(1-x*x))
  float ss = side * side;
  float at = atan2f(side, 1.0f + sqrtf(1.0f - ss));
  nang = 2.0f * (2.0f * at);
  meas = m;
}

__global__ __launch_bounds__(256) void wmeasure_kernel(
    const float4* __restrict__ inp, const float4* __restrict__ ang,
    const float4* __restrict__ lres, float* __restrict__ out,
    int n4, int n) {
#pragma clang fp contract(off)
  int i = blockIdx.x * blockDim.x + threadIdx.x;
  if (i >= n4) return;

  float4 vi = inp[i];
  float4 va = ang[i];
  float4 vl = lres[i];

  const float* pi_ = reinterpret_cast<const float*>(&vi);
  const float* pa_ = reinterpret_cast<const float*>(&va);
  const float* pl_ = reinterpret_cast<const float*>(&vl);

  float4 vm, vn;
  float* pm_ = reinterpret_cast<float*>(&vm);
  float* pn_ = reinterpret_cast<float*>(&vn);

  uint32_t base = ((uint32_t)i) << 2;
#pragma unroll
  for (int j = 0; j < 4; ++j) {
    compute_one(pi_[j], pa_[j], pl_[j], base + (uint32_t)j, pm_[j], pn_[j]);
  }

  reinterpret_cast<float4*>(out)[i] = vm;          // meas_res  [0 .. n)
  reinterpret_cast<float4*>(out + n)[i] = vn;      // new_angles [n .. 2n)
}

extern "C" void kernel_launch(void* const* d_in, const int* in_sizes, int n_in,
                              void* d_out, int out_size, void* d_ws,
                              size_t ws_size, hipStream_t stream) {
  const float* inp = (const float*)d_in[0];
  const float* ang = (const float*)d_in[1];
  const float* lr  = (const float*)d_in[2];
  float* out = (float*)d_out;

  int n = in_sizes[0];          // 4096*8192 = 33,554,432 (divisible by 4)
  int n4 = n >> 2;
  int blocks = (n4 + 255) / 256;

  wmeasure_kernel<<<blocks, 256, 0, stream>>>(
      (const float4*)inp, (const float4*)ang, (const float4*)lr, out, n4, n);
}

// Round 11
// 527.807 us; speedup vs baseline: 1.0472x; 1.0472x over previous
//
#include <hip/hip_runtime.h>
#include <cstdint>

#pragma clang fp contract(off)

// ---------------------------------------------------------------------------
// threefry2x32 with key (0, 42)  [= jax.random.key(42)] — FROZEN (bit-exact,
// validated PASS r9). Partitionable path: counter (0, i), bits = x0 ^ x1.
// ---------------------------------------------------------------------------
__device__ __forceinline__ uint32_t rotl32(uint32_t x, uint32_t r) {
  return (x << r) | (x >> (32u - r));
}

__device__ __forceinline__ uint32_t threefry_bits(uint32_t idx) {
  const uint32_t ks0 = 0u;
  const uint32_t ks1 = 42u;
  const uint32_t ks2 = 0x1BD11BDAu ^ 0u ^ 42u;
  uint32_t x0 = 0u + ks0;
  uint32_t x1 = idx + ks1;
#define TF_R(r) { x0 += x1; x1 = rotl32(x1, r); x1 ^= x0; }
  TF_R(13u) TF_R(15u) TF_R(26u) TF_R(6u)
  x0 += ks1; x1 += ks2 + 1u;
  TF_R(17u) TF_R(29u) TF_R(16u) TF_R(24u)
  x0 += ks2; x1 += ks0 + 2u;
  TF_R(13u) TF_R(15u) TF_R(26u) TF_R(6u)
  x0 += ks0; x1 += ks1 + 3u;
  TF_R(17u) TF_R(29u) TF_R(16u) TF_R(24u)
  x0 += ks1; x1 += ks2 + 4u;
  TF_R(13u) TF_R(15u) TF_R(26u) TF_R(6u)
  x0 += ks2; x1 += ks0 + 5u;
#undef TF_R
  return x0 ^ x1;
}

// ---------------------------------------------------------------------------
// XLA Eigen no-FMA tanh — FROZEN (feeds the meas_res compare; validated r9).
// ---------------------------------------------------------------------------
__device__ __forceinline__ float xla_fast_tanh(float x) {
  const float kClamp = 7.90531110763549805f;
  float abs_x = fabsf(x);
  float xc = fminf(fmaxf(x, -kClamp), kClamp);
  float x2 = xc * xc;
  float num = -2.76076847742355e-16f;
  num = num * x2; num = num + 2.00018790482477e-13f;
  num = num * x2; num = num + -8.60467152213735e-11f;
  num = num * x2; num = num + 5.12229709037114e-08f;
  num = num * x2; num = num + 1.48572235717979e-05f;
  num = num * x2; num = num + 6.37261928875436e-04f;
  num = num * x2; num = num + 4.89352455891786e-03f;
  num = xc * num;
  float den = 1.19825839466702e-06f;
  den = den * x2; den = den + 1.18534705686654e-04f;
  den = den * x2; den = den + 2.26843463243900e-03f;
  den = den * x2; den = den + 4.89352518554385e-03f;
  float r = num / den;
  return (abs_x < 0.0004f) ? x : r;
}

// ---------------------------------------------------------------------------
// Inline atan core for s in [-1,1], odd minimax deg-15, |err| ~1e-7.
// Replaces ocml atan2f: our args are always (y in [-1,1], x in [1,2]) so all
// quadrant/inf/nan handling is dead. atan-internal error is ADDITIVE in
// new_angles (not asin-boundary-amplified) — budget ~1e-2, cost ~1e-7.
// FMA allowed here (tail is not bit-frozen).
// ---------------------------------------------------------------------------
__device__ __forceinline__ float atan_core(float s) {
  float t = s * s;
  float r = -4.0540580e-3f;
  r = __builtin_fmaf(r, t, 2.18612288e-2f);
  r = __builtin_fmaf(r, t, -5.59098861e-2f);
  r = __builtin_fmaf(r, t, 9.64200441e-2f);
  r = __builtin_fmaf(r, t, -1.390853351e-1f);
  r = __builtin_fmaf(r, t, 1.994653599e-1f);
  r = __builtin_fmaf(r, t, -3.332985605e-1f);
  r = __builtin_fmaf(r, t, 9.999993329e-1f);
  return s * r;  // sign flows through s; atan(1) -> 0.785398126 (pi/4 + 3.7e-8)
}

// ---------------------------------------------------------------------------
// One element. meas chain + `side` are byte-identical to the r9 PASS kernel.
// ---------------------------------------------------------------------------
__device__ __forceinline__ void compute_one(float in_v, float ang_v, float lr_v,
                                            uint32_t idx, float& meas,
                                            float& nang) {
  const float kHalfPi = 1.5707963267948966f;
  const float kSinG   = 0.7071067811865476f;

  float t = xla_fast_tanh(in_v * 2.0f);
  float theta = kHalfPi * (lr_v - t);
  float temp = ang_v + theta;
  float h = temp * 0.5f;
  float be, co;
  sincosf(h, &be, &co);                         // == sinf+cosf (compiler's own
                                                // sincos fold asserts equality)
  float exp_z = (co * co) - (be * be);
  float e = exp_z * kSinG;
  float onepe = 1.0f + e;                       // shared: p0 numerator & denr(m=+1)
  float oneme = 1.0f - e;                       // shared: p1 numerator & denr(m=-1)
  float p0 = fmaxf(onepe * 0.5f, 0.0f);
  float p1 = fmaxf(oneme * 0.5f, 0.0f);
  float ratio = p0 / (p0 + p1);

  uint32_t bits = threefry_bits(idx);
  float u = __uint_as_float((bits >> 9) | 0x3f800000u) - 1.0f;
  bool pos = (u < ratio);
  float m = pos ? 1.0f : -1.0f;

  // side: FROZEN IEEE (div+sqrt) — selects reuse the exact same fp values the
  // reference computes (1 -/+ m*kSinG const-folds identically; 1 + m*e == onepe/oneme).
  float numr = pos ? (1.0f - kSinG) : (1.0f + kSinG);
  float denr = pos ? onepe : oneme;
  float side = be * sqrtf(numr / denr);
  side = fminf(fmaxf(side, -1.0f), 1.0f);

  // new_angles tail (approx-tolerant): asin(side) = 2*atan(side/(1+sqrt(1-side^2)))
  float ss = side * side;
  float sq = __builtin_amdgcn_sqrtf(1.0f - ss);          // 1-ulp HW sqrt: abs err
                                                         // tiny where sensitive
  float s  = side * __builtin_amdgcn_rcpf(1.0f + sq);    // 1-ulp HW rcp
  nang = 4.0f * atan_core(s);
  meas = m;
}

__global__ __launch_bounds__(256) void wmeasure_kernel(
    const float4* __restrict__ inp, const float4* __restrict__ ang,
    const float4* __restrict__ lres, float* __restrict__ out,
    int n4, int n) {
#pragma clang fp contract(off)
  int i = blockIdx.x * blockDim.x + threadIdx.x;
  if (i >= n4) return;

  float4 vi = inp[i];
  float4 va = ang[i];
  float4 vl = lres[i];

  const float* pi_ = reinterpret_cast<const float*>(&vi);
  const float* pa_ = reinterpret_cast<const float*>(&va);
  const float* pl_ = reinterpret_cast<const float*>(&vl);

  float4 vm, vn;
  float* pm_ = reinterpret_cast<float*>(&vm);
  float* pn_ = reinterpret_cast<float*>(&vn);

  uint32_t base = ((uint32_t)i) << 2;
#pragma unroll
  for (int j = 0; j < 4; ++j) {
    compute_one(pi_[j], pa_[j], pl_[j], base + (uint32_t)j, pm_[j], pn_[j]);
  }

  reinterpret_cast<float4*>(out)[i] = vm;          // meas_res  [0 .. n)
  reinterpret_cast<float4*>(out + n)[i] = vn;      // new_angles [n .. 2n)
}

extern "C" void kernel_launch(void* const* d_in, const int* in_sizes, int n_in,
                              void* d_out, int out_size, void* d_ws,
                              size_t ws_size, hipStream_t stream) {
  const float* inp = (const float*)d_in[0];
  const float* ang = (const float*)d_in[1];
  const float* lr  = (const float*)d_in[2];
  float* out = (float*)d_out;

  int n = in_sizes[0];
  int n4 = n >> 2;
  int blocks = (n4 + 255) / 256;

  wmeasure_kernel<<<blocks, 256, 0, stream>>>(
      (const float4*)inp, (const float4*)ang, (const float4*)lr, out, n4, n);
}